// Round 8
// baseline (1089.744 us; speedup 1.0000x reference)
//
#include <hip/hip_runtime.h>
#include <hip/hip_fp16.h>
#include <math.h>

// RETAIN layer: B=256, T=512, D=128. fp32 compute, f16 h-state storage.
// retain_gru_v3: 256 blocks (1/CU), 768 threads (12 waves).
//   Thread owns 4 consecutive output cols x 32 rows (128 weight VGPRs, no AGPR
//   spill; round-4's 192-reg layout spilled -> v_accvgpr traffic doubled VALU).
//   Per step: matvec (quarter-dots, one ds_write_b128 of partials) | syncthreads |
//   combiner (128 gate threads; e-pipeline on idle wave-2 threads) | raw barrier
//   (lgkmcnt-only wait: hB/e global stores drain under next matvec, not at the
//   barrier -- round-4's __syncthreads vmcnt(0) drained them every step).
//   e[b,t]=h_t.Walpha via 2-stage pipeline (partials at t+1, sum at t+2) ->
//   no 6-deep shuffle chain on the critical path. Length-pair balancing kept.
// retain_attn_h: round-4 proven structure, split 4x over t (grid 1024).
// ws: hB [B][T][128] f16 (33.5 MB) + e [B][T] f32 (0.5 MB).

#define BATCH 256
#define TLEN  512
#define DDIM  128
#define G3    384

static const size_t HB_SZ = (size_t)BATCH * TLEN * DDIM;  // f16 elems
static const size_t E_SZ  = (size_t)BATCH * TLEN;         // f32 elems

__device__ __forceinline__ int clamp_len(int l) {
    return l < 1 ? 1 : (l > TLEN ? TLEN : l);
}
__device__ __forceinline__ float sigm_f(float s) {
    s = fminf(fmaxf(s, -30.f), 30.f);
    return __fdividef(1.f, 1.f + __expf(-s));
}
__device__ __forceinline__ float tanh_f(float u) {
    u = fminf(fmaxf(u, -15.f), 15.f);
    const float e2 = __expf(2.f * u);
    return __fdividef(e2 - 1.f, e2 + 1.f);
}

// ---------------- persistent length-balanced fused GRU, v3 ----------------
__global__ __launch_bounds__(768, 3) void retain_gru_v3(
    const float* __restrict__ x, const int* __restrict__ lengths,
    const float* __restrict__ Wa, const float* __restrict__ Ua,
    const float* __restrict__ ba_in, const float* __restrict__ ba_rec,
    const float* __restrict__ Wb, const float* __restrict__ Ub,
    const float* __restrict__ bb_in, const float* __restrict__ bb_rec,
    const float* __restrict__ W_alpha, const float* __restrict__ b_alpha,
    __half* __restrict__ hB, float* __restrict__ e)
{
    const int g   = blockIdx.x & 1;
    const int ip  = blockIdx.x >> 1;            // 0..127
    const int tid = threadIdx.x;
    const int m   = (tid >= 384) ? 1 : 0;       // 0: X-side (W), 1: U-side
    const int tp  = tid - 384 * m;              // 0..383
    const int q   = tp / 96;                    // row quarter 0..3
    const int c4  = (tp - q * 96) * 4;          // output col base (0..380)

    __shared__ int lensh[BATCH];
    __shared__ int rank2b[BATCH];
    __shared__ __align__(16) float xsh[2][DDIM];
    __shared__ __align__(16) float hsh[2][DDIM];
    __shared__ __align__(16) float parts[2][4][G3];
    __shared__ __align__(16) float walsh[DDIM];
    __shared__ __align__(16) float ep8[2][8];

    if (tid < BATCH) lensh[tid] = clamp_len(lengths[tid]);
    if (tid < DDIM)  walsh[tid] = W_alpha[tid];
    __syncthreads();
    if (tid < BATCH) {                           // stable descending rank-sort
        const int myl = lensh[tid];
        int rank = 0;
        for (int j = 0; j < BATCH; ++j) {
            const int lj = lensh[j];
            rank += (lj > myl) || (lj == myl && j < tid);
        }
        rank2b[rank] = tid;
    }

    // weights: 4 consecutive cols x 32 rows -> 128 VGPRs (fits cap 170)
    const float* __restrict__ Mw = m ? (g ? Ub : Ua) : (g ? Wb : Wa);
    float W0[32], W1[32], W2[32], W3[32];
    #pragma unroll
    for (int r = 0; r < 32; ++r) {
        const float4 wv = *reinterpret_cast<const float4*>(Mw + (size_t)(q * 32 + r) * G3 + c4);
        W0[r] = wv.x; W1[r] = wv.y; W2[r] = wv.z; W3[r] = wv.w;
    }

    float bi0 = 0, bi1 = 0, bi2 = 0, br0 = 0, br1 = 0, br2 = 0, balv = 0;
    if (tid < DDIM) {
        const float* bi = g ? bb_in  : ba_in;
        const float* br = g ? bb_rec : ba_rec;
        bi0 = bi[tid]; bi1 = bi[tid + 128]; bi2 = bi[tid + 256];
        br0 = br[tid]; br1 = br[tid + 128]; br2 = br[tid + 256];
    }
    if (tid == 136) balv = b_alpha[0];
    __syncthreads();

    for (int jj = 0; jj < 2; ++jj) {
        const int b   = rank2b[jj ? 255 - ip : ip];
        const int len = lensh[b];
        if (tid < DDIM) {
            hsh[1][tid] = 0.f;                   // h_{-1}
            xsh[0][tid] = x[((size_t)b * TLEN + (len - 1)) * DDIM + tid];
        }
        __syncthreads();

        for (int t = 0; t < len; ++t) {
            float xnext = 0.f;
            if (tid < DDIM) {                    // prefetch next reversed row
                int rn = len - 2 - t; if (rn < 0) rn = 0;
                xnext = x[((size_t)b * TLEN + rn) * DDIM + tid];
            }
            // quarter matvec: 128 FMAs, 8 b128 broadcast reads
            const float* __restrict__ vh = (m ? hsh[(t + 1) & 1] : xsh[t & 1]) + q * 32;
            float A0 = 0.f, A1 = 0.f, A2 = 0.f, A3 = 0.f;
            #pragma unroll
            for (int rr = 0; rr < 32; rr += 4) {
                const float4 v = *reinterpret_cast<const float4*>(vh + rr);
                A0 = fmaf(v.x, W0[rr+0], A0); A1 = fmaf(v.x, W1[rr+0], A1);
                A2 = fmaf(v.x, W2[rr+0], A2); A3 = fmaf(v.x, W3[rr+0], A3);
                A0 = fmaf(v.y, W0[rr+1], A0); A1 = fmaf(v.y, W1[rr+1], A1);
                A2 = fmaf(v.y, W2[rr+1], A2); A3 = fmaf(v.y, W3[rr+1], A3);
                A0 = fmaf(v.z, W0[rr+2], A0); A1 = fmaf(v.z, W1[rr+2], A1);
                A2 = fmaf(v.z, W2[rr+2], A2); A3 = fmaf(v.z, W3[rr+2], A3);
                A0 = fmaf(v.w, W0[rr+3], A0); A1 = fmaf(v.w, W1[rr+3], A1);
                A2 = fmaf(v.w, W2[rr+3], A2); A3 = fmaf(v.w, W3[rr+3], A3);
            }
            *reinterpret_cast<float4*>(&parts[m][q][c4]) = float4{A0, A1, A2, A3};
            __syncthreads();                     // bar1 (full; x-prefetch lands here)

            if (tid < DDIM) {                    // gate combiner (2 waves)
                const int d = tid;
                const float xz = bi0 + parts[0][0][d]     + parts[0][1][d]     + parts[0][2][d]     + parts[0][3][d];
                const float xr = bi1 + parts[0][0][128+d] + parts[0][1][128+d] + parts[0][2][128+d] + parts[0][3][128+d];
                const float xh = bi2 + parts[0][0][256+d] + parts[0][1][256+d] + parts[0][2][256+d] + parts[0][3][256+d];
                const float rz = br0 + parts[1][0][d]     + parts[1][1][d]     + parts[1][2][d]     + parts[1][3][d];
                const float rr_= br1 + parts[1][0][128+d] + parts[1][1][128+d] + parts[1][2][128+d] + parts[1][3][128+d];
                const float rh = br2 + parts[1][0][256+d] + parts[1][1][256+d] + parts[1][2][256+d] + parts[1][3][256+d];
                const float z  = sigm_f(xz + rz);
                const float r_ = sigm_f(xr + rr_);
                const float hh = tanh_f(xh + r_ * rh);
                const float hn = z * hsh[(t + 1) & 1][d] + (1.f - z) * hh;
                hsh[t & 1][d] = hn;
                xsh[(t + 1) & 1][d] = xnext;
                if (g) hB[((size_t)b * TLEN + t) * DDIM + d] = __float2half(hn);
            } else if (!g && tid >= 128 && tid < 136) {
                if (t >= 1) {                    // partials of e[t-1] = h_{t-1}.Walpha
                    const int k0 = (tid - 128) * 16;
                    const float* hp = hsh[(t + 1) & 1];
                    float s = 0.f;
                    #pragma unroll
                    for (int i2 = 0; i2 < 16; i2 += 4) {
                        const float4 hv = *reinterpret_cast<const float4*>(hp + k0 + i2);
                        const float4 wv = *reinterpret_cast<const float4*>(&walsh[k0 + i2]);
                        s = fmaf(hv.w, wv.w, fmaf(hv.z, wv.z, fmaf(hv.y, wv.y, fmaf(hv.x, wv.x, s))));
                    }
                    ep8[(t + 1) & 1][tid - 128] = s;
                }
            } else if (!g && tid == 136 && t >= 2) {   // finalize e[t-2]
                float s = balv;
                #pragma unroll
                for (int i2 = 0; i2 < 8; ++i2) s += ep8[t & 1][i2];
                e[(size_t)b * TLEN + (t - 2)] = s;
            }
            // raw barrier: wait LDS only; hB/e stores drain under next matvec
            asm volatile("s_waitcnt lgkmcnt(0)" ::: "memory");
            __builtin_amdgcn_s_barrier();
            __builtin_amdgcn_sched_barrier(0);
        }

        // e pipeline tails (g=0 only)
        if (!g && tid >= 128 && tid < 136) {     // partials of e[len-1]
            const int k0 = (tid - 128) * 16;
            const float* hp = hsh[(len + 1) & 1];
            float s = 0.f;
            #pragma unroll
            for (int i2 = 0; i2 < 16; i2 += 4) {
                const float4 hv = *reinterpret_cast<const float4*>(hp + k0 + i2);
                const float4 wv = *reinterpret_cast<const float4*>(&walsh[k0 + i2]);
                s = fmaf(hv.w, wv.w, fmaf(hv.z, wv.z, fmaf(hv.y, wv.y, fmaf(hv.x, wv.x, s))));
            }
            ep8[(len + 1) & 1][tid - 128] = s;
        } else if (!g && tid == 136 && len >= 2) {  // finalize e[len-2]
            float s = balv;
            #pragma unroll
            for (int i2 = 0; i2 < 8; ++i2) s += ep8[len & 1][i2];
            e[(size_t)b * TLEN + (len - 2)] = s;
        }
        __syncthreads();
        if (!g && tid == 136) {                   // finalize e[len-1]
            float s = balv;
            #pragma unroll
            for (int i2 = 0; i2 < 8; ++i2) s += ep8[(len + 1) & 1][i2];
            e[(size_t)b * TLEN + (len - 1)] = s;
        }
        __syncthreads();
    }
}

// ---------------- attn: softmax(e) + tanh(h@Wbeta) + weighted sum ----------------
// grid = 1024 (4 blocks per b, t-split 128 each), block = 256 (d = tid&127, rh = tid>>7)
__global__ __launch_bounds__(256, 4) void retain_attn_h(
    const float* __restrict__ x, const int* __restrict__ lengths,
    const float* __restrict__ W_beta, const float* __restrict__ b_beta,
    const __half* __restrict__ hB, const float* __restrict__ eb,
    float* __restrict__ out)
{
    const int bid = blockIdx.x;
    const int b   = bid >> 2;
    const int tq  = bid & 3;
    const int len = clamp_len(lengths[b]);
    const float* __restrict__ e = eb + (size_t)b * TLEN;

    const int tid = threadIdx.x;
    const int d   = tid & 127;
    const int rh  = tid >> 7;

    float Wreg[64];
    #pragma unroll
    for (int rr = 0; rr < 64; rr++) Wreg[rr] = W_beta[(rh * 64 + rr) * DDIM + d];
    const float bb = b_beta[d];

    __shared__ float se[512];
    __shared__ float red[256];
    __shared__ __align__(16) float h2[2][128];
    __shared__ float part[2][2][128];

    for (int idx = tid; idx < 512; idx += 256) {
        const int tc = idx < len ? idx : len - 1;   // mask carry-forward
        se[idx] = e[tc];
    }
    __syncthreads();
    red[tid] = fmaxf(se[tid], se[tid + 256]);
    __syncthreads();
    for (int s = 128; s > 0; s >>= 1) {
        if (tid < s) red[tid] = fmaxf(red[tid], red[tid + s]);
        __syncthreads();
    }
    const float mx = red[0];
    __syncthreads();
    const float s0 = expf(se[tid] - mx), s1 = expf(se[tid + 256] - mx);
    se[tid] = s0; se[tid + 256] = s1;
    red[tid] = s0 + s1;
    __syncthreads();
    for (int s = 128; s > 0; s >>= 1) {
        if (tid < s) red[tid] += red[tid + s];
        __syncthreads();
    }
    const float inv = 1.f / red[0];
    __syncthreads();

    const int tbase = tq * 128;
    float acc = 0.f;
    for (int tp = 0; tp < 128; tp += 2) {
        const int t0 = tbase + tp;
        {
            const int t  = t0 + rh;
            const int tc = t < len ? t : len - 1;
            h2[rh][d] = __half2float(hB[((size_t)b * TLEN + tc) * DDIM + d]);
        }
        __syncthreads();
        float p0 = 0.f, p1 = 0.f;
        #pragma unroll
        for (int rr = 0; rr < 64; rr += 4) {
            const float4 ha = *reinterpret_cast<const float4*>(&h2[0][rh * 64 + rr]);
            const float4 hb = *reinterpret_cast<const float4*>(&h2[1][rh * 64 + rr]);
            p0 = fmaf(ha.x, Wreg[rr + 0], p0);
            p0 = fmaf(ha.y, Wreg[rr + 1], p0);
            p0 = fmaf(ha.z, Wreg[rr + 2], p0);
            p0 = fmaf(ha.w, Wreg[rr + 3], p0);
            p1 = fmaf(hb.x, Wreg[rr + 0], p1);
            p1 = fmaf(hb.y, Wreg[rr + 1], p1);
            p1 = fmaf(hb.z, Wreg[rr + 2], p1);
            p1 = fmaf(hb.w, Wreg[rr + 3], p1);
        }
        part[rh][0][d] = p0;
        part[rh][1][d] = p1;
        __syncthreads();
        if (rh == 0) {
            #pragma unroll
            for (int ti = 0; ti < 2; ti++) {
                const int t = t0 + ti;
                const float v  = tanhf(part[0][ti][d] + part[1][ti][d] + bb);
                const float al = se[t] * inv;
                const float xv = x[((size_t)b * TLEN + t) * DDIM + d];
                acc = fmaf(al * v, xv, acc);
            }
        }
        __syncthreads();
    }
    if (rh == 0) atomicAdd(&out[b * DDIM + d], acc);
}

extern "C" void kernel_launch(void* const* d_in, const int* in_sizes, int n_in,
                              void* d_out, int out_size, void* d_ws, size_t ws_size,
                              hipStream_t stream)
{
    const float* x       = (const float*)d_in[0];
    const int*   lengths = (const int*)  d_in[1];
    const float* Wa      = (const float*)d_in[2];
    const float* Ua      = (const float*)d_in[3];
    const float* ba_in   = (const float*)d_in[4];
    const float* ba_rec  = (const float*)d_in[5];
    const float* Wb      = (const float*)d_in[6];
    const float* Ub      = (const float*)d_in[7];
    const float* bb_in   = (const float*)d_in[8];
    const float* bb_rec  = (const float*)d_in[9];
    const float* W_alpha = (const float*)d_in[10];
    const float* b_alpha = (const float*)d_in[11];
    const float* W_beta  = (const float*)d_in[12];
    const float* b_beta  = (const float*)d_in[13];
    float* out = (float*)d_out;

    const size_t need = HB_SZ * sizeof(__half) + E_SZ * sizeof(float);  // ~34.1 MB
    if (ws_size < need) return;

    __half* hB = (__half*)d_ws;
    float*  e  = (float*)((char*)d_ws + HB_SZ * sizeof(__half));

    hipMemsetAsync(d_out, 0, (size_t)out_size * sizeof(float), stream);
    retain_gru_v3<<<256, 768, 0, stream>>>(
        x, lengths, Wa, Ua, ba_in, ba_rec, Wb, Ub, bb_in, bb_rec, W_alpha, b_alpha, hB, e);
    retain_attn_h<<<1024, 256, 0, stream>>>(x, lengths, W_beta, b_beta, hB, e, out);
}